// Round 18
// baseline (126.735 us; speedup 1.0000x reference)
//
#include <hip/hip_runtime.h>

#define NNODES 10000
#define NHEADS 8
#define DHEAD 64
#define FEAT 512
#define NNETS 3
#define EDGES 160000
#define ETOT (NNETS * EDGES)
#define NBUCK 4
#define BUCKSZ 2500             // nodes per src-bucket
#define NKEY (NNODES * NBUCK)   // 40000 counting-sort keys

#define CVTX_BLKS 5000          // NNODES*FEAT/4/256
#define CVTW_BLKS 256           // (FEAT/32)^2
#define HIST_BLKS 1875          // ETOT/256
#define INV_BLKS 40             // ceil(NNODES/256)
#define SCAT_BLKS 1875          // ETOT/256
#define GEMM_BLKS 316           // 4 * 79
#define AGG_BLKS 2048           // aggregate grid (grid-stride over 2500)

typedef unsigned short ushort_t;
typedef __bf16 bf16x8 __attribute__((ext_vector_type(8)));
typedef float f32x4 __attribute__((ext_vector_type(4)));
typedef unsigned u32x4 __attribute__((ext_vector_type(4)));

static __device__ __forceinline__ ushort_t f2b(float f) {
    unsigned u = __float_as_uint(f);
    unsigned r = u + 0x7FFF + ((u >> 16) & 1);   // RNE
    return (ushort_t)(r >> 16);
}

static __device__ __forceinline__ void mfma16(f32x4& d, bf16x8 a, bf16x8 b) {
    asm volatile("v_mfma_f32_16x16x32_bf16 %0, %1, %2, %0" : "+v"(d) : "v"(a), "v"(b));
}

#define GLDS(gp, lp)                                                                     \
    __builtin_amdgcn_global_load_lds((const __attribute__((address_space(1))) void*)(gp), \
                                     (__attribute__((address_space(3))) void*)(lp), 16, 0, 0)

// ---- fused prep: cvt_x | cvt_wt(permuted cols) | hist(dst*4+srcbucket) | build_inv ----
// wbt row n' = d*8+h  <-  original W column n = h*64+d, so the GEMM's output columns
// are already in [D][H] order and the epilogue writes contiguous lines.
__global__ __launch_bounds__(256) void prep_fused_kernel(
    const float* __restrict__ x, ushort_t* __restrict__ xb, const float* __restrict__ W,
    ushort_t* __restrict__ wbt, const int* __restrict__ edges, int* __restrict__ counts,
    const int* __restrict__ n_id, int* __restrict__ inv) {
    __shared__ float tile[32][33];
    int b = blockIdx.x;
    int t = threadIdx.x;
    if (b < CVTX_BLKS) {
        int i = (b * 256 + t) * 4;
        float4 v = *(const float4*)(x + i);
        ushort4 o;
        o.x = f2b(v.x);
        o.y = f2b(v.y);
        o.z = f2b(v.z);
        o.w = f2b(v.w);
        *(ushort4*)(xb + i) = o;
    } else if (b < CVTX_BLKS + CVTW_BLKS) {
        int bb = b - CVTX_BLKS;
        int n0 = (bb & 15) * 32, k0 = (bb >> 4) * 32;
        int r = t >> 3, c4 = (t & 7) * 4;
        float4 v = *(const float4*)(&W[(size_t)(k0 + r) * FEAT + n0 + c4]);
        tile[r][c4 + 0] = v.x;
        tile[r][c4 + 1] = v.y;
        tile[r][c4 + 2] = v.z;
        tile[r][c4 + 3] = v.w;
        __syncthreads();
        ushort4 o;
        o.x = f2b(tile[c4 + 0][r]);
        o.y = f2b(tile[c4 + 1][r]);
        o.z = f2b(tile[c4 + 2][r]);
        o.w = f2b(tile[c4 + 3][r]);
        int ncol = n0 + r;                          // original col = h*64+d
        int nperm = (ncol & 63) * 8 + (ncol >> 6);  // permuted row = d*8+h
        *(ushort4*)(&wbt[(size_t)nperm * FEAT + k0 + c4]) = o;
    } else if (b < CVTX_BLKS + CVTW_BLKS + HIST_BLKS) {
        int eid = (b - CVTX_BLKS - CVTW_BLKS) * 256 + t;
        int net = eid / EDGES;
        int e = eid - net * EDGES;
        int srcg = edges[net * (2 * EDGES) + e];
        int dstg = edges[net * (2 * EDGES) + EDGES + e];
        atomicAdd(&counts[dstg * NBUCK + srcg / BUCKSZ], 1);
    } else {
        int i = (b - CVTX_BLKS - CVTW_BLKS - HIST_BLKS) * 256 + t;
        if (i < NNODES) inv[n_id[i]] = i;
    }
}

// ---- shfl-based exclusive scan of counts[NKEY] -> offsets[NKEY+1]; zeros cursor ----
// 1024 threads; threads 0..999 each own 40 contiguous counters.
__global__ __launch_bounds__(1024) void scan_kernel(const int* __restrict__ counts,
                                                    int* __restrict__ offsets,
                                                    int* __restrict__ cursor) {
    __shared__ int wincl[16];
    int t = threadIdx.x;
    int ln = t & 63;
    int w = t >> 6;
    int4 v[10];
    int mysum = 0;
    if (t < 1000) {
        const int4* cp = (const int4*)(counts + t * 40);
#pragma unroll
        for (int i = 0; i < 10; ++i) {
            v[i] = cp[i];
            mysum += v[i].x + v[i].y + v[i].z + v[i].w;
        }
        // zero cursor in parallel (no dependency on the scan)
        int4* zp = (int4*)(cursor + t * 40);
        int4 z = make_int4(0, 0, 0, 0);
#pragma unroll
        for (int i = 0; i < 10; ++i) zp[i] = z;
    }
    // inclusive scan of thread sums within wave
    int s = mysum;
#pragma unroll
    for (int o = 1; o < 64; o <<= 1) {
        int u = __shfl_up(s, o, 64);
        if (ln >= o) s += u;
    }
    if (ln == 63) wincl[w] = s;
    __syncthreads();
    if (w == 0) {
        int ws = (ln < 16) ? wincl[ln] : 0;
#pragma unroll
        for (int o = 1; o < 16; o <<= 1) {
            int u = __shfl_up(ws, o, 64);
            if (ln >= o) ws += u;
        }
        if (ln < 16) wincl[ln] = ws;
    }
    __syncthreads();
    int base = ((w > 0) ? wincl[w - 1] : 0) + s - mysum;  // global exclusive base
    if (t < 1000) {
        int running = base;
        int* op = offsets + t * 40;
#pragma unroll
        for (int i = 0; i < 10; ++i) {
            op[i * 4 + 0] = running; running += v[i].x;
            op[i * 4 + 1] = running; running += v[i].y;
            op[i * 4 + 2] = running; running += v[i].z;
            op[i * 4 + 3] = running; running += v[i].w;
        }
        if (t == 999) offsets[NKEY] = running;
    }
}

// ---- fused: gemm (blocks 0..315, dispatched FIRST) | scatter (blocks 316..2190) ----
// gemm: hfeat = xb @ wbt^T; wbt cols pre-permuted so output IS [N][D][H],
//       epilogue writes 16-lane-contiguous bf16 (full lines, no RMW).
// scatter: 32B-aligned edge record {srcoff, pad x3, alpha[8]bf16}, full-sector writes.
// gemm first: its latency-bound 316 blocks start immediately; scatter's wide
// memory work fills the machine around them, leaving a BW-wide (not narrow) tail.
__global__ __launch_bounds__(256) void gemm_scatter_kernel(
    const ushort_t* __restrict__ xb, const ushort_t* __restrict__ wbt,
    ushort_t* __restrict__ Cq, const int* __restrict__ edges,
    const int* __restrict__ inv, const int* __restrict__ offsets,
    int* __restrict__ cursor, const float* __restrict__ attns,
    const float* __restrict__ nw, unsigned* __restrict__ rec) {
    const int t = threadIdx.x;
    if (blockIdx.x >= GEMM_BLKS) {
        int eid = (blockIdx.x - GEMM_BLKS) * 256 + t;
        int net = eid / EDGES;
        int e = eid - net * EDGES;
        int srcg = edges[net * (2 * EDGES) + e];
        int dstg = edges[net * (2 * EDGES) + EDGES + e];
        int key = dstg * NBUCK + srcg / BUCKSZ;
        int pos = offsets[key] + atomicAdd(&cursor[key], 1);
        float4 A0 = *(const float4*)(&attns[(size_t)eid * NHEADS]);
        float4 A1 = *(const float4*)(&attns[(size_t)eid * NHEADS + 4]);
        u32x4 w0, w1;
        w0.x = (unsigned)(inv[srcg] << 10);  // byte offset of hfeat row (1024 B/row)
        w0.y = 0; w0.z = 0; w0.w = 0;
        w1.x = (unsigned)f2b(A0.x * nw[0 * NNETS + net]) |
               ((unsigned)f2b(A0.y * nw[1 * NNETS + net]) << 16);
        w1.y = (unsigned)f2b(A0.z * nw[2 * NNETS + net]) |
               ((unsigned)f2b(A0.w * nw[3 * NNETS + net]) << 16);
        w1.z = (unsigned)f2b(A1.x * nw[4 * NNETS + net]) |
               ((unsigned)f2b(A1.y * nw[5 * NNETS + net]) << 16);
        w1.w = (unsigned)f2b(A1.z * nw[6 * NNETS + net]) |
               ((unsigned)f2b(A1.w * nw[7 * NNETS + net]) << 16);
        *(u32x4*)(&rec[(size_t)pos * 8]) = w0;
        *(u32x4*)(&rec[(size_t)pos * 8 + 4]) = w1;
        return;
    }
    __shared__ ushort_t Alds[128 * 32];
    __shared__ ushort_t Blds[128 * 32];
    const int gb = blockIdx.x;
    const int wv = t >> 6;
    const int l = t & 63;
    const int lane15 = l & 15;
    const int hi = l >> 4;
    const int r0 = (gb >> 2) * 128;
    const int c0 = (gb & 3) * 128;
    const int WR = (wv >> 1) * 64;
    const int WC = (wv & 1) * 64;

    const int srow = (wv << 4) + (l >> 2);
    const int scol = (l & 3) << 3;
    const ushort_t* Ab0 = xb + (size_t)min(r0 + srow, NNODES - 1) * FEAT + scol;
    const ushort_t* Ab1 = xb + (size_t)min(r0 + 64 + srow, NNODES - 1) * FEAT + scol;
    const ushort_t* Bb0 = wbt + (size_t)(c0 + srow) * FEAT + scol;
    const ushort_t* Bb1 = wbt + (size_t)(c0 + 64 + srow) * FEAT + scol;
    ushort_t* Al0 = &Alds[wv * 512];
    ushort_t* Al1 = &Alds[2048 + wv * 512];
    ushort_t* Bl0 = &Blds[wv * 512];
    ushort_t* Bl1 = &Blds[2048 + wv * 512];

    f32x4 acc[4][4] = {};

    for (int k0 = 0; k0 < FEAT; k0 += 32) {
        GLDS(Ab0 + k0, Al0);
        GLDS(Ab1 + k0, Al1);
        GLDS(Bb0 + k0, Bl0);
        GLDS(Bb1 + k0, Bl1);
        __syncthreads();
        bf16x8 a[4], b[4];
        const ushort_t* Ap = &Alds[(WR + lane15) * 32 + hi * 8];
        const ushort_t* Bp = &Blds[(WC + lane15) * 32 + hi * 8];
#pragma unroll
        for (int m = 0; m < 4; ++m) a[m] = *(const bf16x8*)(Ap + m * 512);
#pragma unroll
        for (int n = 0; n < 4; ++n) b[n] = *(const bf16x8*)(Bp + n * 512);
#pragma unroll
        for (int m = 0; m < 4; ++m)
#pragma unroll
            for (int n = 0; n < 4; ++n) mfma16(acc[m][n], a[m], b[n]);
        __syncthreads();
    }
    asm volatile("s_nop 7\n\ts_nop 7\n\ts_nop 7" ::);  // MFMA->VALU hazard guard
#pragma unroll
    for (int m = 0; m < 4; ++m) {
#pragma unroll
        for (int rr = 0; rr < 4; ++rr) {
            int row = r0 + WR + m * 16 + hi * 4 + rr;
            if (row < NNODES) {
#pragma unroll
                for (int n = 0; n < 4; ++n) {
                    int col = c0 + WC + n * 16 + lane15;  // already [D][H]-ordered
                    Cq[(size_t)row * FEAT + col] = f2b(acc[m][n][rr]);
                }
            }
        }
    }
}

// ---- aggregation: 4 waves, 1 node/wave, 4-edge groups, 8 blocks/CU, grid-stride ----
static __device__ __forceinline__ void fma_pair(unsigned a, unsigned h, float& lo,
                                                float& hi) {
    float alo = __uint_as_float(a << 16);
    float ahi = __uint_as_float(a & 0xFFFF0000u);
    float hlo = __uint_as_float(h << 16);
    float hhi = __uint_as_float(h & 0xFFFF0000u);
    lo = fmaf(alo, hlo, lo);
    hi = fmaf(ahi, hhi, hi);
}

__global__ __launch_bounds__(256, 8) void aggregate_kernel(
    const unsigned* __restrict__ rec, const int* __restrict__ offsets,
    const int* __restrict__ n_id, const ushort_t* __restrict__ hfeatq,
    const float* __restrict__ bias, float* __restrict__ out) {
    int wv = threadIdx.x >> 6;
    int d = threadIdx.x & 63;
    const char* hb = (const char*)hfeatq + d * 16;  // lane's 16B column slice
    for (int gb = blockIdx.x; gb < NNODES / 4; gb += AGG_BLKS) {
        int n = gb * 4 + wv;
        int g = n_id[n];
        int beg = offsets[g * NBUCK], end = offsets[g * NBUCK + NBUCK];
        float acc[8] = {};
        int k = beg;
        for (; k + 4 <= end; k += 4) {
            unsigned so0 = rec[(size_t)(k + 0) * 8];
            unsigned so1 = rec[(size_t)(k + 1) * 8];
            unsigned so2 = rec[(size_t)(k + 2) * 8];
            unsigned so3 = rec[(size_t)(k + 3) * 8];
            u32x4 g0 = *(const u32x4*)(hb + so0);
            u32x4 g1 = *(const u32x4*)(hb + so1);
            u32x4 g2 = *(const u32x4*)(hb + so2);
            u32x4 g3 = *(const u32x4*)(hb + so3);
            u32x4 a0 = *(const u32x4*)(&rec[(size_t)(k + 0) * 8 + 4]);
            u32x4 a1 = *(const u32x4*)(&rec[(size_t)(k + 1) * 8 + 4]);
            u32x4 a2 = *(const u32x4*)(&rec[(size_t)(k + 2) * 8 + 4]);
            u32x4 a3 = *(const u32x4*)(&rec[(size_t)(k + 3) * 8 + 4]);
            fma_pair(a0.x, g0.x, acc[0], acc[1]);
            fma_pair(a0.y, g0.y, acc[2], acc[3]);
            fma_pair(a0.z, g0.z, acc[4], acc[5]);
            fma_pair(a0.w, g0.w, acc[6], acc[7]);
            fma_pair(a1.x, g1.x, acc[0], acc[1]);
            fma_pair(a1.y, g1.y, acc[2], acc[3]);
            fma_pair(a1.z, g1.z, acc[4], acc[5]);
            fma_pair(a1.w, g1.w, acc[6], acc[7]);
            fma_pair(a2.x, g2.x, acc[0], acc[1]);
            fma_pair(a2.y, g2.y, acc[2], acc[3]);
            fma_pair(a2.z, g2.z, acc[4], acc[5]);
            fma_pair(a2.w, g2.w, acc[6], acc[7]);
            fma_pair(a3.x, g3.x, acc[0], acc[1]);
            fma_pair(a3.y, g3.y, acc[2], acc[3]);
            fma_pair(a3.z, g3.z, acc[4], acc[5]);
            fma_pair(a3.w, g3.w, acc[6], acc[7]);
        }
        for (; k < end; ++k) {
            unsigned so = rec[(size_t)k * 8];
            u32x4 a0 = *(const u32x4*)(&rec[(size_t)k * 8 + 4]);
            u32x4 g0 = *(const u32x4*)(hb + so);
            fma_pair(a0.x, g0.x, acc[0], acc[1]);
            fma_pair(a0.y, g0.y, acc[2], acc[3]);
            fma_pair(a0.z, g0.z, acc[4], acc[5]);
            fma_pair(a0.w, g0.w, acc[6], acc[7]);
        }
#pragma unroll
        for (int h = 0; h < NHEADS; ++h) {
            int c = h * DHEAD + d;
            __builtin_nontemporal_store(acc[h] + bias[c], &out[(size_t)n * FEAT + c]);
        }
    }
}

extern "C" void kernel_launch(void* const* d_in, const int* in_sizes, int n_in,
                              void* d_out, int out_size, void* d_ws, size_t ws_size,
                              hipStream_t stream) {
    const float* x = (const float*)d_in[0];
    const int* n_id = (const int*)d_in[1];
    const float* attns = (const float*)d_in[2];
    const int* edges = (const int*)d_in[3];
    const float* nw = (const float*)d_in[4];
    const float* W = (const float*)d_in[5];
    const float* bias = (const float*)d_in[6];
    float* out = (float*)d_out;

    char* ws = (char*)d_ws;
    size_t o = 0;
    ushort_t* hfeatq = (ushort_t*)(ws + o); o += 10240000;   // [N][64][8] bf16
    unsigned* rec    = (unsigned*)(ws + o); o += 15360000;   // [Etot] 32B edge records
    ushort_t* xb     = (ushort_t*)(ws + o); o += 10240000;
    ushort_t* wbt    = (ushort_t*)(ws + o); o += 524288;
    int* counts      = (int*)(ws + o);      o += 160000;     // NKEY
    int* cursor      = (int*)(ws + o);      o += 160000;     // NKEY
    int* offsets     = (int*)(ws + o);      o += 160004;     // NKEY+1
    int* inv         = (int*)(ws + o);      o += 40000;
    // total ~36.9 MB

    hipMemsetAsync(counts, 0, 160000, stream);  // counts only; cursor zeroed in scan
    prep_fused_kernel<<<CVTX_BLKS + CVTW_BLKS + HIST_BLKS + INV_BLKS, 256, 0, stream>>>(
        x, xb, W, wbt, edges, counts, n_id, inv);
    scan_kernel<<<1, 1024, 0, stream>>>(counts, offsets, cursor);
    gemm_scatter_kernel<<<GEMM_BLKS + SCAT_BLKS, 256, 0, stream>>>(
        xb, wbt, hfeatq, edges, inv, offsets, cursor, attns, nw, rec);
    aggregate_kernel<<<AGG_BLKS, 256, 0, stream>>>(rec, offsets, n_id, hfeatq, bias,
                                                   out);
}

// Round 20
// 120.885 us; speedup vs baseline: 1.0484x; 1.0484x over previous
//
#include <hip/hip_runtime.h>

#define NNODES 10000
#define NHEADS 8
#define DHEAD 64
#define FEAT 512
#define NNETS 3
#define EDGES 160000
#define ETOT (NNETS * EDGES)
#define NBUCK 4
#define BUCKSZ 2500             // nodes per src-bucket
#define NKEY (NNODES * NBUCK)   // 40000 counting-sort keys

#define CVTX_BLKS 5000          // NNODES*FEAT/4/256
#define CVTW_BLKS 256           // (FEAT/32)^2
#define HIST_BLKS 1875          // ETOT/256
#define INV_BLKS 40             // ceil(NNODES/256)
#define SCAT_BLKS 1875          // ETOT/256
#define GEMM_BLKS 316           // 4 * 79

typedef unsigned short ushort_t;
typedef __bf16 bf16x8 __attribute__((ext_vector_type(8)));
typedef float f32x4 __attribute__((ext_vector_type(4)));
typedef unsigned u32x4 __attribute__((ext_vector_type(4)));

static __device__ __forceinline__ ushort_t f2b(float f) {
    unsigned u = __float_as_uint(f);
    unsigned r = u + 0x7FFF + ((u >> 16) & 1);   // RNE
    return (ushort_t)(r >> 16);
}

static __device__ __forceinline__ void mfma16(f32x4& d, bf16x8 a, bf16x8 b) {
    asm volatile("v_mfma_f32_16x16x32_bf16 %0, %1, %2, %0" : "+v"(d) : "v"(a), "v"(b));
}

#define GLDS(gp, lp)                                                                     \
    __builtin_amdgcn_global_load_lds((const __attribute__((address_space(1))) void*)(gp), \
                                     (__attribute__((address_space(3))) void*)(lp), 16, 0, 0)

// ---- zero counts+cursor (kernel, not memset node: solid graph ordering) ----
__global__ __launch_bounds__(256) void zero_kernel(int4* __restrict__ p) {
    int i = blockIdx.x * 256 + threadIdx.x;
    if (i < 20000) p[i] = make_int4(0, 0, 0, 0);  // 80000 ints = counts + cursor
}

// ---- fused prep: cvt_x | cvt_wt(permuted cols) | hist(dst*4+srcbucket) | build_inv ----
// wbt row n' = d*8+h  <-  original W column n = h*64+d, so the GEMM's output columns
// are already in [D][H] order and the epilogue writes contiguous lines.
__global__ __launch_bounds__(256) void prep_fused_kernel(
    const float* __restrict__ x, ushort_t* __restrict__ xb, const float* __restrict__ W,
    ushort_t* __restrict__ wbt, const int* __restrict__ edges, int* __restrict__ counts,
    const int* __restrict__ n_id, int* __restrict__ inv) {
    __shared__ float tile[32][33];
    int b = blockIdx.x;
    int t = threadIdx.x;
    if (b < CVTX_BLKS) {
        int i = (b * 256 + t) * 4;
        float4 v = *(const float4*)(x + i);
        ushort4 o;
        o.x = f2b(v.x);
        o.y = f2b(v.y);
        o.z = f2b(v.z);
        o.w = f2b(v.w);
        *(ushort4*)(xb + i) = o;
    } else if (b < CVTX_BLKS + CVTW_BLKS) {
        int bb = b - CVTX_BLKS;
        int n0 = (bb & 15) * 32, k0 = (bb >> 4) * 32;
        int r = t >> 3, c4 = (t & 7) * 4;
        float4 v = *(const float4*)(&W[(size_t)(k0 + r) * FEAT + n0 + c4]);
        tile[r][c4 + 0] = v.x;
        tile[r][c4 + 1] = v.y;
        tile[r][c4 + 2] = v.z;
        tile[r][c4 + 3] = v.w;
        __syncthreads();
        ushort4 o;
        o.x = f2b(tile[c4 + 0][r]);
        o.y = f2b(tile[c4 + 1][r]);
        o.z = f2b(tile[c4 + 2][r]);
        o.w = f2b(tile[c4 + 3][r]);
        int ncol = n0 + r;                          // original col = h*64+d
        int nperm = (ncol & 63) * 8 + (ncol >> 6);  // permuted row = d*8+h
        *(ushort4*)(&wbt[(size_t)nperm * FEAT + k0 + c4]) = o;
    } else if (b < CVTX_BLKS + CVTW_BLKS + HIST_BLKS) {
        int eid = (b - CVTX_BLKS - CVTW_BLKS) * 256 + t;
        int net = eid / EDGES;
        int e = eid - net * EDGES;
        int srcg = edges[net * (2 * EDGES) + e];
        int dstg = edges[net * (2 * EDGES) + EDGES + e];
        atomicAdd(&counts[dstg * NBUCK + srcg / BUCKSZ], 1);
    } else {
        int i = (b - CVTX_BLKS - CVTW_BLKS - HIST_BLKS) * 256 + t;
        if (i < NNODES) inv[n_id[i]] = i;
    }
}

// ---- shfl-based exclusive scan of counts[NKEY] -> offsets[NKEY+1] ----
// 1024 threads; threads 0..999 each own 40 contiguous counters.
__global__ __launch_bounds__(1024) void scan_kernel(const int* __restrict__ counts,
                                                    int* __restrict__ offsets) {
    __shared__ int wincl[16];
    int t = threadIdx.x;
    int ln = t & 63;
    int w = t >> 6;
    int4 v[10];
    int mysum = 0;
    if (t < 1000) {
        const int4* cp = (const int4*)(counts + t * 40);
#pragma unroll
        for (int i = 0; i < 10; ++i) {
            v[i] = cp[i];
            mysum += v[i].x + v[i].y + v[i].z + v[i].w;
        }
    }
    // inclusive scan of thread sums within wave
    int s = mysum;
#pragma unroll
    for (int o = 1; o < 64; o <<= 1) {
        int u = __shfl_up(s, o, 64);
        if (ln >= o) s += u;
    }
    if (ln == 63) wincl[w] = s;
    __syncthreads();
    if (w == 0) {
        int ws = (ln < 16) ? wincl[ln] : 0;
#pragma unroll
        for (int o = 1; o < 16; o <<= 1) {
            int u = __shfl_up(ws, o, 64);
            if (ln >= o) ws += u;
        }
        if (ln < 16) wincl[ln] = ws;
    }
    __syncthreads();
    int base = ((w > 0) ? wincl[w - 1] : 0) + s - mysum;  // global exclusive base
    if (t < 1000) {
        int running = base;
        int* op = offsets + t * 40;
#pragma unroll
        for (int i = 0; i < 10; ++i) {
            op[i * 4 + 0] = running; running += v[i].x;
            op[i * 4 + 1] = running; running += v[i].y;
            op[i * 4 + 2] = running; running += v[i].z;
            op[i * 4 + 3] = running; running += v[i].w;
        }
        if (t == 999) offsets[NKEY] = running;
    }
}

// ---- fused: gemm (blocks 0..315, dispatched FIRST) | scatter (blocks 316..2190) ----
// gemm: hfeat = xb @ wbt^T; wbt cols pre-permuted so output IS [N][D][H],
//       epilogue writes 16-lane-contiguous bf16 (full lines, no RMW).
// scatter: 32B-aligned edge record {srcoff, pad x3, alpha[8]bf16}, full-sector writes.
// gemm first: its latency-bound 316 blocks start immediately; scatter's wide
// memory work fills the machine around them, leaving a BW-wide (not narrow) tail.
__global__ __launch_bounds__(256) void gemm_scatter_kernel(
    const ushort_t* __restrict__ xb, const ushort_t* __restrict__ wbt,
    ushort_t* __restrict__ Cq, const int* __restrict__ edges,
    const int* __restrict__ inv, const int* __restrict__ offsets,
    int* __restrict__ cursor, const float* __restrict__ attns,
    const float* __restrict__ nw, unsigned* __restrict__ rec) {
    const int t = threadIdx.x;
    if (blockIdx.x >= GEMM_BLKS) {
        int eid = (blockIdx.x - GEMM_BLKS) * 256 + t;
        int net = eid / EDGES;
        int e = eid - net * EDGES;
        int srcg = edges[net * (2 * EDGES) + e];
        int dstg = edges[net * (2 * EDGES) + EDGES + e];
        int key = dstg * NBUCK + srcg / BUCKSZ;
        int pos = offsets[key] + atomicAdd(&cursor[key], 1);
        float4 A0 = *(const float4*)(&attns[(size_t)eid * NHEADS]);
        float4 A1 = *(const float4*)(&attns[(size_t)eid * NHEADS + 4]);
        u32x4 w0, w1;
        w0.x = (unsigned)(inv[srcg] << 10);  // byte offset of hfeat row (1024 B/row)
        w0.y = 0; w0.z = 0; w0.w = 0;
        w1.x = (unsigned)f2b(A0.x * nw[0 * NNETS + net]) |
               ((unsigned)f2b(A0.y * nw[1 * NNETS + net]) << 16);
        w1.y = (unsigned)f2b(A0.z * nw[2 * NNETS + net]) |
               ((unsigned)f2b(A0.w * nw[3 * NNETS + net]) << 16);
        w1.z = (unsigned)f2b(A1.x * nw[4 * NNETS + net]) |
               ((unsigned)f2b(A1.y * nw[5 * NNETS + net]) << 16);
        w1.w = (unsigned)f2b(A1.z * nw[6 * NNETS + net]) |
               ((unsigned)f2b(A1.w * nw[7 * NNETS + net]) << 16);
        *(u32x4*)(&rec[(size_t)pos * 8]) = w0;
        *(u32x4*)(&rec[(size_t)pos * 8 + 4]) = w1;
        return;
    }
    __shared__ ushort_t Alds[128 * 32];
    __shared__ ushort_t Blds[128 * 32];
    const int gb = blockIdx.x;
    const int wv = t >> 6;
    const int l = t & 63;
    const int lane15 = l & 15;
    const int hi = l >> 4;
    const int r0 = (gb >> 2) * 128;
    const int c0 = (gb & 3) * 128;
    const int WR = (wv >> 1) * 64;
    const int WC = (wv & 1) * 64;

    const int srow = (wv << 4) + (l >> 2);
    const int scol = (l & 3) << 3;
    const ushort_t* Ab0 = xb + (size_t)min(r0 + srow, NNODES - 1) * FEAT + scol;
    const ushort_t* Ab1 = xb + (size_t)min(r0 + 64 + srow, NNODES - 1) * FEAT + scol;
    const ushort_t* Bb0 = wbt + (size_t)(c0 + srow) * FEAT + scol;
    const ushort_t* Bb1 = wbt + (size_t)(c0 + 64 + srow) * FEAT + scol;
    ushort_t* Al0 = &Alds[wv * 512];
    ushort_t* Al1 = &Alds[2048 + wv * 512];
    ushort_t* Bl0 = &Blds[wv * 512];
    ushort_t* Bl1 = &Blds[2048 + wv * 512];

    f32x4 acc[4][4] = {};

    for (int k0 = 0; k0 < FEAT; k0 += 32) {
        GLDS(Ab0 + k0, Al0);
        GLDS(Ab1 + k0, Al1);
        GLDS(Bb0 + k0, Bl0);
        GLDS(Bb1 + k0, Bl1);
        __syncthreads();
        bf16x8 a[4], b[4];
        const ushort_t* Ap = &Alds[(WR + lane15) * 32 + hi * 8];
        const ushort_t* Bp = &Blds[(WC + lane15) * 32 + hi * 8];
#pragma unroll
        for (int m = 0; m < 4; ++m) a[m] = *(const bf16x8*)(Ap + m * 512);
#pragma unroll
        for (int n = 0; n < 4; ++n) b[n] = *(const bf16x8*)(Bp + n * 512);
#pragma unroll
        for (int m = 0; m < 4; ++m)
#pragma unroll
            for (int n = 0; n < 4; ++n) mfma16(acc[m][n], a[m], b[n]);
        __syncthreads();
    }
    asm volatile("s_nop 7\n\ts_nop 7\n\ts_nop 7" ::);  // MFMA->VALU hazard guard
#pragma unroll
    for (int m = 0; m < 4; ++m) {
#pragma unroll
        for (int rr = 0; rr < 4; ++rr) {
            int row = r0 + WR + m * 16 + hi * 4 + rr;
            if (row < NNODES) {
#pragma unroll
                for (int n = 0; n < 4; ++n) {
                    int col = c0 + WC + n * 16 + lane15;  // already [D][H]-ordered
                    Cq[(size_t)row * FEAT + col] = f2b(acc[m][n][rr]);
                }
            }
        }
    }
}

// ---- aggregation: 4 waves, 1 node/wave, 4-edge groups, 8 blocks/CU ----
static __device__ __forceinline__ void fma_pair(unsigned a, unsigned h, float& lo,
                                                float& hi) {
    float alo = __uint_as_float(a << 16);
    float ahi = __uint_as_float(a & 0xFFFF0000u);
    float hlo = __uint_as_float(h << 16);
    float hhi = __uint_as_float(h & 0xFFFF0000u);
    lo = fmaf(alo, hlo, lo);
    hi = fmaf(ahi, hhi, hi);
}

__global__ __launch_bounds__(256, 8) void aggregate_kernel(
    const unsigned* __restrict__ rec, const int* __restrict__ offsets,
    const int* __restrict__ n_id, const ushort_t* __restrict__ hfeatq,
    const float* __restrict__ bias, float* __restrict__ out) {
    int wv = threadIdx.x >> 6;
    int d = threadIdx.x & 63;
    const char* hb = (const char*)hfeatq + d * 16;  // lane's 16B column slice
    int n = blockIdx.x * 4 + wv;
    int g = n_id[n];
    int beg = offsets[g * NBUCK], end = offsets[g * NBUCK + NBUCK];
    float acc[8] = {};
    int k = beg;
    for (; k + 4 <= end; k += 4) {
        unsigned so0 = rec[(size_t)(k + 0) * 8];
        unsigned so1 = rec[(size_t)(k + 1) * 8];
        unsigned so2 = rec[(size_t)(k + 2) * 8];
        unsigned so3 = rec[(size_t)(k + 3) * 8];
        u32x4 g0 = *(const u32x4*)(hb + so0);
        u32x4 g1 = *(const u32x4*)(hb + so1);
        u32x4 g2 = *(const u32x4*)(hb + so2);
        u32x4 g3 = *(const u32x4*)(hb + so3);
        u32x4 a0 = *(const u32x4*)(&rec[(size_t)(k + 0) * 8 + 4]);
        u32x4 a1 = *(const u32x4*)(&rec[(size_t)(k + 1) * 8 + 4]);
        u32x4 a2 = *(const u32x4*)(&rec[(size_t)(k + 2) * 8 + 4]);
        u32x4 a3 = *(const u32x4*)(&rec[(size_t)(k + 3) * 8 + 4]);
        fma_pair(a0.x, g0.x, acc[0], acc[1]);
        fma_pair(a0.y, g0.y, acc[2], acc[3]);
        fma_pair(a0.z, g0.z, acc[4], acc[5]);
        fma_pair(a0.w, g0.w, acc[6], acc[7]);
        fma_pair(a1.x, g1.x, acc[0], acc[1]);
        fma_pair(a1.y, g1.y, acc[2], acc[3]);
        fma_pair(a1.z, g1.z, acc[4], acc[5]);
        fma_pair(a1.w, g1.w, acc[6], acc[7]);
        fma_pair(a2.x, g2.x, acc[0], acc[1]);
        fma_pair(a2.y, g2.y, acc[2], acc[3]);
        fma_pair(a2.z, g2.z, acc[4], acc[5]);
        fma_pair(a2.w, g2.w, acc[6], acc[7]);
        fma_pair(a3.x, g3.x, acc[0], acc[1]);
        fma_pair(a3.y, g3.y, acc[2], acc[3]);
        fma_pair(a3.z, g3.z, acc[4], acc[5]);
        fma_pair(a3.w, g3.w, acc[6], acc[7]);
    }
    for (; k < end; ++k) {
        unsigned so = rec[(size_t)k * 8];
        u32x4 a0 = *(const u32x4*)(&rec[(size_t)k * 8 + 4]);
        u32x4 g0 = *(const u32x4*)(hb + so);
        fma_pair(a0.x, g0.x, acc[0], acc[1]);
        fma_pair(a0.y, g0.y, acc[2], acc[3]);
        fma_pair(a0.z, g0.z, acc[4], acc[5]);
        fma_pair(a0.w, g0.w, acc[6], acc[7]);
    }
#pragma unroll
    for (int h = 0; h < NHEADS; ++h) {
        int c = h * DHEAD + d;
        __builtin_nontemporal_store(acc[h] + bias[c], &out[(size_t)n * FEAT + c]);
    }
}

extern "C" void kernel_launch(void* const* d_in, const int* in_sizes, int n_in,
                              void* d_out, int out_size, void* d_ws, size_t ws_size,
                              hipStream_t stream) {
    const float* x = (const float*)d_in[0];
    const int* n_id = (const int*)d_in[1];
    const float* attns = (const float*)d_in[2];
    const int* edges = (const int*)d_in[3];
    const float* nw = (const float*)d_in[4];
    const float* W = (const float*)d_in[5];
    const float* bias = (const float*)d_in[6];
    float* out = (float*)d_out;

    char* ws = (char*)d_ws;
    size_t o = 0;
    ushort_t* hfeatq = (ushort_t*)(ws + o); o += 10240000;   // [N][64][8] bf16
    unsigned* rec    = (unsigned*)(ws + o); o += 15360000;   // [Etot] 32B edge records
    ushort_t* xb     = (ushort_t*)(ws + o); o += 10240000;
    ushort_t* wbt    = (ushort_t*)(ws + o); o += 524288;
    int* counts      = (int*)(ws + o);      o += 160000;     // NKEY
    int* cursor      = (int*)(ws + o);      o += 160000;     // NKEY (adjacent to counts)
    int* offsets     = (int*)(ws + o);      o += 160004;     // NKEY+1
    int* inv         = (int*)(ws + o);      o += 40000;
    // total ~36.9 MB

    zero_kernel<<<79, 256, 0, stream>>>((int4*)counts);  // counts + cursor
    prep_fused_kernel<<<CVTX_BLKS + CVTW_BLKS + HIST_BLKS + INV_BLKS, 256, 0, stream>>>(
        x, xb, W, wbt, edges, counts, n_id, inv);
    scan_kernel<<<1, 1024, 0, stream>>>(counts, offsets);
    gemm_scatter_kernel<<<GEMM_BLKS + SCAT_BLKS, 256, 0, stream>>>(
        xb, wbt, hfeatq, edges, inv, offsets, cursor, attns, nw, rec);
    aggregate_kernel<<<NNODES / 4, 256, 0, stream>>>(rec, offsets, n_id, hfeatq, bias,
                                                     out);
}